// Round 5
// baseline (400.412 us; speedup 1.0000x reference)
//
#include <hip/hip_runtime.h>
#include <hip/hip_bf16.h>

typedef __bf16 bf16;
typedef __bf16 v8bf __attribute__((ext_vector_type(8)));
typedef float f32x4 __attribute__((ext_vector_type(4)));

#define BB 16
#define CCH 128
#define HH 96
#define WW 96
#define EE 6
#define HP 98

static constexpr size_t XP_ELEMS   = (size_t)BB * HP * HP * CCH;   // padded x, bf16 channel-last
static constexpr size_t WT1S_ELEMS = (size_t)EE * 36 * 4096;       // [e][q*9+tap][128 row][32 cin] swizzled
static constexpr size_t WT2S_ELEMS = (size_t)EE * 4 * 4096;        // [e][kc][128 row][32 cin] swizzled
static constexpr size_t XP_BYTES   = XP_ELEMS * 2;
static constexpr size_t WT1S_BYTES = WT1S_ELEMS * 2;
static constexpr size_t WT2S_BYTES = WT2S_ELEMS * 2;

__device__ inline bf16 to_bf16(float f) { return (bf16)f; }

// async global->LDS, 16B/lane; LDS dest = wave-uniform base + lane*16
__device__ __forceinline__ void gload16(const bf16* gsrc, bf16* ldst) {
    __builtin_amdgcn_global_load_lds(
        (const __attribute__((address_space(1))) unsigned int*)gsrc,
        (__attribute__((address_space(3))) unsigned int*)ldst, 16, 0, 0);
}

// full-bank XOR swizzle over the 4 granule slots
__device__ __forceinline__ int fsw(int r) { return (r & 3) ^ ((r >> 2) & 3); }

#define WAITVM(N) asm volatile("s_waitcnt vmcnt(" #N ")" ::: "memory")
#define WAITLGKM0 asm volatile("s_waitcnt lgkmcnt(0)" ::: "memory")

// ---------------- zero the 1-px halo of xp ----------------
__global__ void border_kernel(bf16* __restrict__ xp) {
    const int b = blockIdx.x;
    bf16* xpb = xp + (size_t)b * HP * HP * CCH;
    uint4 z; z.x = z.y = z.z = z.w = 0u;
    for (int k = threadIdx.x; k < 388 * 16; k += 256) {
        int cell = k >> 4, gci = k & 15;
        int y, xx;
        if      (cell < 98)  { y = 0;              xx = cell; }
        else if (cell < 196) { y = 97;             xx = cell - 98; }
        else if (cell < 292) { y = cell - 196 + 1; xx = 0; }
        else                 { y = cell - 292 + 1; xx = 97; }
        *reinterpret_cast<uint4*>(xpb + ((size_t)y * HP + xx) * CCH + gci * 8) = z;
    }
}

// ---------------- pad + layout transform + per-(b,y) channel row sums ----------------
__global__ void pad_kernel(const float* __restrict__ x, bf16* __restrict__ xp,
                           float* __restrict__ meanpart) {
    __shared__ float tile[WW][CCH + 2];
    __shared__ float part[2][CCH];
    const int y = blockIdx.x;
    const int b = blockIdx.y;
    const int t = threadIdx.x;
    const float* src = x + (size_t)b * CCH * HH * WW + (size_t)y * WW;
    for (int i = t; i < CCH * WW; i += 256) {
        int c = i / WW;
        int xx = i - c * WW;
        tile[xx][c] = src[(size_t)c * HH * WW + xx];
    }
    __syncthreads();
    bf16* dst = xp + (((size_t)b * HP + (y + 1)) * HP + 1) * CCH;
    for (int j = t; j < WW * CCH; j += 256) {
        int xx = j >> 7;
        int c = j & 127;
        dst[(size_t)xx * CCH + c] = to_bf16(tile[xx][c]);
    }
    const int c = t & 127, half = t >> 7;
    float s = 0.f;
    for (int xx = half * 48; xx < half * 48 + 48; ++xx) s += tile[xx][c];
    part[half][c] = s;
    __syncthreads();
    if (t < 128) meanpart[((size_t)b * HH + y) * CCH + t] = part[0][t] + part[1][t];
}

__global__ void reduce_mean_kernel(const float* __restrict__ meanpart, float* __restrict__ meanbc) {
    int bc = blockIdx.x * 256 + threadIdx.x;     // < 2048
    int b = bc >> 7, c = bc & 127;
    float s = 0.f;
    for (int y = 0; y < HH; ++y) s += meanpart[((size_t)b * HH + y) * CCH + c];
    meanbc[bc] = s * (1.f / (HH * WW));
}

// ---------------- weight transform into swizzled chunk layouts ----------------
__global__ void wt_kernel(const float* __restrict__ w1, const float* __restrict__ w2,
                          bf16* __restrict__ wt1s, bf16* __restrict__ wt2s) {
    const int idx = blockIdx.x * 256 + threadIdx.x;
    const int W1N = (int)WT1S_ELEMS;
    if (idx < W1N) {
        int o = idx & 4095;
        int lo = o & 7, gs = (o >> 3) & 3, row = o >> 5;
        int cg = idx >> 12;                 // 0..215
        int e = cg / 36, c = cg - e * 36;
        int q = c / 9, tap = c - q * 9;
        int g = gs ^ ((row & 3) ^ ((row >> 2) & 3));
        int cin = q * 32 + g * 8 + lo;
        wt1s[idx] = to_bf16(w1[((size_t)(e * CCH + row) * CCH + cin) * 9 + tap]);
    } else if (idx < W1N + (int)WT2S_ELEMS) {
        int j2 = idx - W1N;
        int o = j2 & 4095;
        int lo = o & 7, gs = (o >> 3) & 3, row = o >> 5;
        int cg = j2 >> 12;                  // 0..23
        int e = cg >> 2, kc = cg & 3;
        int g = gs ^ ((row & 3) ^ ((row >> 2) & 3));
        int cin = kc * 32 + g * 8 + lo;
        wt2s[j2] = to_bf16(w2[(size_t)(e * CCH + row) * CCH + cin]);
    }
}

// ---------------- router: parallel logits, then per-b softmax/top-2 (f64, semantics preserved) ----------------
__global__ void router_kernel(const float* __restrict__ meanbc, const float* __restrict__ Wr,
                              const float* __restrict__ br, int* __restrict__ eidx,
                              float* __restrict__ gval, float* __restrict__ total_out) {
    __shared__ double logits_s[BB][EE];
    __shared__ double probs[BB][EE];
    const int t = threadIdx.x;
    if (t < BB * EE) {                    // 96 threads: one (b,e) dot each
        const int b = t / EE, e = t - (t / EE) * EE;
        double s = (double)br[e];
        for (int c = 0; c < CCH; ++c)
            s += (double)meanbc[b * CCH + c] * (double)Wr[c * EE + e];
        if (s > 10.0) s = 10.0;
        if (s < -10.0) s = -10.0;
        logits_s[b][e] = s;
    }
    __syncthreads();
    if (t < BB) {
        const int b = t;
        double mx = logits_s[b][0];
        for (int e = 1; e < EE; ++e) mx = fmax(mx, logits_s[b][e]);
        double den = 0.0, p[EE];
        for (int e = 0; e < EE; ++e) { p[e] = exp(logits_s[b][e] - mx); den += p[e]; }
        for (int e = 0; e < EE; ++e) {
            p[e] /= den;
            if (p[e] < 1e-6) p[e] = 1e-6;
            if (p[e] > 1.0)  p[e] = 1.0;
            probs[b][e] = p[e];
        }
        int e0 = 0;
        for (int e = 1; e < EE; ++e) if (p[e] > p[e0]) e0 = e;
        int e1 = (e0 == 0) ? 1 : 0;
        for (int e = 0; e < EE; ++e) if (e != e0 && p[e] > p[e1]) e1 = e;
        double s2 = p[e0] + p[e1] + 1e-8;
        eidx[b * 2 + 0] = e0;
        eidx[b * 2 + 1] = e1;
        gval[b * 2 + 0] = (float)(p[e0] / s2);
        gval[b * 2 + 1] = (float)(p[e1] / s2);
    }
    __syncthreads();
    if (t == 0) {
        double usage[EE] = {0, 0, 0, 0, 0, 0};
        double ent = 0.0;
        for (int b = 0; b < BB; ++b) {
            double eb = 0.0;
            for (int e = 0; e < EE; ++e) {
                double pv = probs[b][e];
                usage[e] += pv;
                eb -= pv * log(pv + 1e-10);
            }
            ent += eb;
        }
        ent /= (double)BB;
        double lb = 0.0;
        for (int e = 0; e < EE; ++e) {
            double u = usage[e] / (double)BB - 1.0 / (double)EE;
            lb += u * u;
        }
        *total_out = (float)(lb * 5e-4 - ent * 1e-3);
    }
}

// ---------------- fused MoE conv block ----------------
// grid (72 tiles, B); 256 thr = 4 waves (2x2). Output tile 128 cout x 128 pos.
// R5: operands read ONE PHASE AHEAD — phase p = [WAITVM(chunk p+1); barrier; (patch);
// issue(p+3); ds_read frags(p+1); MFMA(frags p); lgkmcnt(0)]. Ring-3 Abuf, patch dbuf.
__launch_bounds__(256, 2)
__global__ void moe_conv_kernel(const float* __restrict__ x, const bf16* __restrict__ xp,
                                const bf16* __restrict__ wt1s, const bf16* __restrict__ wt2s,
                                const float* __restrict__ b1, const float* __restrict__ b2,
                                const int* __restrict__ eidx, const float* __restrict__ gval,
                                float* __restrict__ out) {
    __shared__ __align__(16) bf16 Patch[2][180 * 32];   // 23040 B
    __shared__ __align__(16) bf16 Abuf[3][128 * 32];    // 24576 B
    __shared__ __align__(16) bf16 Ht[128 * 128];        // 32768 B  -> 80384 B total, 2 blocks/CU

    const int tile = blockIdx.x;
    const int b = blockIdx.y;
    const int ty = tile / 6, tx = tile - ty * 6;
    const int y0 = ty * 8, x0 = tx * 16;

    const int t = threadIdx.x;
    const int lane = t & 63;
    const int w = t >> 6;
    const int wm = w >> 1, wn = w & 1;
    const int lr = lane & 15;
    const int lh = lane >> 4;          // 0..3
    const int lq = lh * 4;

    const bf16* xpb = xp + (size_t)b * HP * HP * CCH;
    const int e0 = eidx[b * 2 + 0], e1 = eidx[b * 2 + 1];
    const float g0 = gval[b * 2 + 0], g1 = gval[b * 2 + 1];

    auto stageA = [&](const bf16* src, bf16* dst) {                 // 2 vmem instr / wave
        #pragma unroll
        for (int rep = 0; rep < 2; ++rep)
            gload16(src + (rep * 256 + t) * 8, dst + (rep * 256 + w * 64) * 8);
    };
    auto stream_base = [&](int s) -> const bf16* {                  // s in [0,80)
        int kk = (s >= 40) ? 1 : 0;
        int ss = s - 40 * kk;
        int e = kk ? e1 : e0;
        return (ss < 36) ? wt1s + ((size_t)e * 36 + ss) * 4096
                         : wt2s + ((size_t)e * 4 + (ss - 36)) * 4096;
    };
    auto issue = [&](int s) { if (s < 80) stageA(stream_base(s), Abuf[s % 3]); };
    auto patch_dma = [&](int q, int pb) {                           // 3 vmem instr / wave
        bf16* base = &Patch[pb][0];
        #pragma unroll
        for (int it = 0; it < 3; ++it) {
            int m = it * 256 + t;
            if (m < 720) {
                int rp = m >> 2, sl = m & 3;
                int g = sl ^ fsw(rp);
                int py = rp / 18, px = rp - py * 18;
                gload16(xpb + ((size_t)(y0 + py) * HP + (x0 + px)) * CCH + q * 32 + g * 8,
                        base + (it * 256 + w * 64) * 8);
            }
        }
    };
    auto ldA = [&](int gp, v8bf* dst) {                             // A-frags of chunk gp
        const bf16* ab = &Abuf[gp % 3][0];
        #pragma unroll
        for (int i = 0; i < 4; ++i) {
            int r = wm * 64 + i * 16 + lr;
            dst[i] = *reinterpret_cast<const v8bf*>(&ab[r * 32 + ((lh ^ fsw(r)) << 3)]);
        }
    };
    auto ldB3 = [&](int qb, int tap, v8bf* dst) {                   // B-frags from Patch[qb]
        const bf16* pb = &Patch[qb][0];
        const int ry = tap / 3, sx = tap - (tap / 3) * 3;
        #pragma unroll
        for (int j = 0; j < 4; ++j) {
            int rp = (wn * 4 + j + ry) * 18 + lr + sx;
            dst[j] = *reinterpret_cast<const v8bf*>(&pb[rp * 32 + ((lh ^ fsw(rp)) << 3)]);
        }
    };

    f32x4 acc1[4][4];      // conv1x1 accumulator (both experts; h pre-scaled by gate)
    #pragma unroll
    for (int i = 0; i < 4; ++i)
        #pragma unroll
        for (int j = 0; j < 4; ++j) { f32x4 z = {0.f,0.f,0.f,0.f}; acc1[i][j] = z; }

    v8bf afc[4], bvc[4];   // current-phase operands (loaded one phase ahead)

    // ---- prologue: patch q0 + chunks 0..2 in flight; preload frags(0) ----
    patch_dma(0, 0);
    issue(0); issue(1); issue(2);
    WAITVM(4);                         // drain patch + chunk 0 (leave ch1, ch2)
    __builtin_amdgcn_s_barrier();
    ldA(0, afc);
    ldB3(0, 0, bvc);
    WAITLGKM0;                         // frags(0) complete before phase-0 barrier

    int p = 0;
    for (int kk2 = 0; kk2 < 2; ++kk2) {
        const int e = kk2 ? e1 : e0;
        const float g = kk2 ? g1 : g0;

        f32x4 acc[4][4];
        #pragma unroll
        for (int i = 0; i < 4; ++i)
            #pragma unroll
            for (int j = 0; j < 4; ++j) { f32x4 z = {0.f,0.f,0.f,0.f}; acc[i][j] = z; }

        // ---- conv3x3: 36 phases, sections s = kk2*4+q ----
        for (int q = 0; q < 4; ++q) {
            const int s = kk2 * 4 + q;
            #pragma unroll
            for (int tap = 0; tap < 9; ++tap, ++p) {
                if (tap == 1 && s < 7) { WAITVM(5); } else { WAITVM(2); }   // chunk p+1 done
                __builtin_amdgcn_s_barrier();
                if (tap == 0 && s < 7) patch_dma((s + 1) & 3, (s + 1) & 1);
                issue(p + 3);

                // read NEXT phase's fragments (overlap with this phase's MFMAs)
                v8bf afn[4], bvn[4];
                ldA(p + 1, afn);
                const bool last3x3 = (tap == 8 && q == 3);
                if (!last3x3) {
                    const int nq  = (tap == 8) ? q + 1 : q;
                    const int ntp = (tap == 8) ? 0 : tap + 1;
                    ldB3(nq & 1, ntp, bvn);
                }

                __builtin_amdgcn_s_setprio(1);
                #pragma unroll
                for (int i = 0; i < 4; ++i)
                    #pragma unroll
                    for (int j = 0; j < 4; ++j)
                        acc[i][j] = __builtin_amdgcn_mfma_f32_16x16x32_bf16(afc[i], bvc[j], acc[i][j], 0, 0, 0);
                __builtin_amdgcn_s_setprio(0);

                WAITLGKM0;             // next-frags complete before the next barrier (ring reuse safety)
                #pragma unroll
                for (int i = 0; i < 4; ++i) afc[i] = afn[i];
                if (!last3x3) {
                    #pragma unroll
                    for (int j = 0; j < 4; ++j) bvc[j] = bvn[j];
                }
            }
        }

        // ---- gelu(acc + b1) * g -> Ht ----
        const float* b1e = b1 + e * CCH;
        #pragma unroll
        for (int i = 0; i < 4; ++i) {
            const int cb = wm * 64 + i * 16 + lq;
            float bias[4];
            #pragma unroll
            for (int q2 = 0; q2 < 4; ++q2) bias[q2] = b1e[cb + q2];
            #pragma unroll
            for (int j = 0; j < 4; ++j) {
                const int pos = wn * 64 + j * 16 + lr;
                bf16 hv[4];
                #pragma unroll
                for (int q2 = 0; q2 < 4; ++q2) {
                    float v = acc[i][j][q2] + bias[q2];
                    float u = 0.7978845608028654f * (v + 0.044715f * v * v * v);
                    float ex = __expf(2.f * u);
                    float th = (ex - 1.f) / (ex + 1.f);
                    hv[q2] = to_bf16(g * (0.5f * v * (1.f + th)));
                }
                const int slot = (cb >> 3) ^ (pos & 7);
                *reinterpret_cast<uint2*>(&Ht[pos * 128 + slot * 8 + (cb & 7)]) =
                    *reinterpret_cast<uint2*>(hv);
            }
        }
        WAITLGKM0;                      // Ht writes drained; published by next phase's barrier

        // ---- conv1x1: 4 phases; af one-ahead, Ht bv in-phase ----
        #pragma unroll
        for (int kc = 0; kc < 4; ++kc, ++p) {
            if (kk2 == 1 && kc >= 2) { WAITVM(0); } else { WAITVM(2); }
            __builtin_amdgcn_s_barrier();
            issue(p + 3);

            v8bf bvh[4];
            #pragma unroll
            for (int j = 0; j < 4; ++j) {
                int pos = wn * 64 + j * 16 + lr;
                int gr = kc * 4 + lh;
                bvh[j] = *reinterpret_cast<const v8bf*>(&Ht[pos * 128 + ((gr ^ (pos & 7)) << 3)]);
            }
            v8bf afn[4];
            if (!(kk2 == 1 && kc == 3)) ldA(p + 1, afn);
            if (kc == 3 && kk2 == 0) ldB3(0, 0, bvc);   // expert-1 (q0,tap0) B-frags, one ahead

            __builtin_amdgcn_s_setprio(1);
            #pragma unroll
            for (int i = 0; i < 4; ++i)
                #pragma unroll
                for (int j = 0; j < 4; ++j)
                    acc1[i][j] = __builtin_amdgcn_mfma_f32_16x16x32_bf16(afc[i], bvh[j], acc1[i][j], 0, 0, 0);
            __builtin_amdgcn_s_setprio(0);

            WAITLGKM0;
            if (!(kk2 == 1 && kc == 3)) {
                #pragma unroll
                for (int i = 0; i < 4; ++i) afc[i] = afn[i];
            }
        }
    }

    // ---- epilogue: out = acc1 + (g0*b2[e0] + g1*b2[e1]) + (g0+g1)*x ----
    const float gsum = g0 + g1;
    #pragma unroll
    for (int i = 0; i < 4; ++i) {
        const int cb = wm * 64 + i * 16 + lq;
        float bs[4];
        #pragma unroll
        for (int q2 = 0; q2 < 4; ++q2)
            bs[q2] = g0 * b2[e0 * CCH + cb + q2] + g1 * b2[e1 * CCH + cb + q2];
        #pragma unroll
        for (int j = 0; j < 4; ++j) {
            const int pos = wn * 64 + j * 16 + lr;
            const int yy = pos >> 4, xx = pos & 15;
            #pragma unroll
            for (int q2 = 0; q2 < 4; ++q2) {
                size_t gi = (((size_t)b * CCH + cb + q2) * HH + (y0 + yy)) * WW + (x0 + xx);
                out[gi] = acc1[i][j][q2] + bs[q2] + gsum * x[gi];
            }
        }
    }
}

extern "C" void kernel_launch(void* const* d_in, const int* in_sizes, int n_in,
                              void* d_out, int out_size, void* d_ws, size_t ws_size,
                              hipStream_t stream) {
    const float* x  = (const float*)d_in[0];
    const float* Wr = (const float*)d_in[1];
    const float* br = (const float*)d_in[2];
    const float* W1 = (const float*)d_in[3];
    const float* b1 = (const float*)d_in[4];
    const float* W2 = (const float*)d_in[5];
    const float* b2 = (const float*)d_in[6];
    float* out = (float*)d_out;

    char* ws = (char*)d_ws;
    bf16* xp    = (bf16*)ws;
    bf16* wt1s  = (bf16*)(ws + XP_BYTES);
    bf16* wt2s  = (bf16*)(ws + XP_BYTES + WT1S_BYTES);
    float* meanpart = (float*)(ws + XP_BYTES + WT1S_BYTES + WT2S_BYTES);
    float* meanbc   = (float*)(ws + XP_BYTES + WT1S_BYTES + WT2S_BYTES + (size_t)BB * HH * CCH * 4);
    int*   eidx     = (int*)(ws + XP_BYTES + WT1S_BYTES + WT2S_BYTES + (size_t)BB * HH * CCH * 4 + BB * CCH * 4);
    float* gvals    = (float*)(ws + XP_BYTES + WT1S_BYTES + WT2S_BYTES + (size_t)BB * HH * CCH * 4 + BB * CCH * 4 + BB * 2 * 4);
    float* total    = out + (size_t)BB * CCH * HH * WW;

    border_kernel<<<BB, 256, 0, stream>>>(xp);
    pad_kernel<<<dim3(HH, BB), 256, 0, stream>>>(x, xp, meanpart);
    reduce_mean_kernel<<<8, 256, 0, stream>>>(meanpart, meanbc);
    wt_kernel<<<(unsigned)((WT1S_ELEMS + WT2S_ELEMS + 255) / 256), 256, 0, stream>>>(W1, W2, wt1s, wt2s);
    router_kernel<<<1, 128, 0, stream>>>(meanbc, Wr, br, eidx, gvals, total);
    moe_conv_kernel<<<dim3(72, BB), 256, 0, stream>>>(x, xp, wt1s, wt2s, b1, b2, eidx, gvals, out);
}

// Round 6
// 261.693 us; speedup vs baseline: 1.5301x; 1.5301x over previous
//
#include <hip/hip_runtime.h>
#include <hip/hip_bf16.h>

typedef __bf16 bf16;
typedef __bf16 v8bf __attribute__((ext_vector_type(8)));
typedef float f32x4 __attribute__((ext_vector_type(4)));

#define BB 16
#define CCH 128
#define HH 96
#define WW 96
#define EE 6
#define HP 98

static constexpr size_t XP_ELEMS   = (size_t)BB * HP * HP * CCH;   // padded x, bf16 channel-last
static constexpr size_t WT1S_ELEMS = (size_t)EE * 36 * 4096;       // [e][q*9+tap][128 row][32 cin] swizzled
static constexpr size_t WT2S_ELEMS = (size_t)EE * 4 * 4096;        // [e][kc][128 row][32 cin] swizzled
static constexpr size_t XP_BYTES   = XP_ELEMS * 2;
static constexpr size_t WT1S_BYTES = WT1S_ELEMS * 2;
static constexpr size_t WT2S_BYTES = WT2S_ELEMS * 2;

__device__ inline bf16 to_bf16(float f) { return (bf16)f; }

// async global->LDS, 16B/lane; LDS dest must be WAVE-UNIFORM (HW adds lane*16)
__device__ __forceinline__ void gload16(const bf16* gsrc, bf16* ldst_wave_uniform) {
    __builtin_amdgcn_global_load_lds(
        (const __attribute__((address_space(1))) unsigned int*)gsrc,
        (__attribute__((address_space(3))) unsigned int*)ldst_wave_uniform, 16, 0, 0);
}

// full-bank XOR swizzle over the 4 granule slots
__device__ __forceinline__ int fsw(int r) { return (r & 3) ^ ((r >> 2) & 3); }

#define WAITVM(N) asm volatile("s_waitcnt vmcnt(" #N ")" ::: "memory")
#define WAITLGKM0 asm volatile("s_waitcnt lgkmcnt(0)" ::: "memory")

// ---------------- zero the 1-px halo of xp ----------------
__global__ void border_kernel(bf16* __restrict__ xp) {
    const int b = blockIdx.x;
    bf16* xpb = xp + (size_t)b * HP * HP * CCH;
    uint4 z; z.x = z.y = z.z = z.w = 0u;
    for (int k = threadIdx.x; k < 388 * 16; k += 256) {
        int cell = k >> 4, gci = k & 15;
        int y, xx;
        if      (cell < 98)  { y = 0;              xx = cell; }
        else if (cell < 196) { y = 97;             xx = cell - 98; }
        else if (cell < 292) { y = cell - 196 + 1; xx = 0; }
        else                 { y = cell - 292 + 1; xx = 97; }
        *reinterpret_cast<uint4*>(xpb + ((size_t)y * HP + xx) * CCH + gci * 8) = z;
    }
}

// ---------------- pad + layout transform + per-(b,y) channel row sums ----------------
__global__ void pad_kernel(const float* __restrict__ x, bf16* __restrict__ xp,
                           float* __restrict__ meanpart) {
    __shared__ float tile[WW][CCH + 2];
    __shared__ float part[2][CCH];
    const int y = blockIdx.x;
    const int b = blockIdx.y;
    const int t = threadIdx.x;
    const float* src = x + (size_t)b * CCH * HH * WW + (size_t)y * WW;
    for (int i = t; i < CCH * WW; i += 256) {
        int c = i / WW;
        int xx = i - c * WW;
        tile[xx][c] = src[(size_t)c * HH * WW + xx];
    }
    __syncthreads();
    bf16* dst = xp + (((size_t)b * HP + (y + 1)) * HP + 1) * CCH;
    for (int j = t; j < WW * CCH; j += 256) {
        int xx = j >> 7;
        int c = j & 127;
        dst[(size_t)xx * CCH + c] = to_bf16(tile[xx][c]);
    }
    const int c = t & 127, half = t >> 7;
    float s = 0.f;
    for (int xx = half * 48; xx < half * 48 + 48; ++xx) s += tile[xx][c];
    part[half][c] = s;
    __syncthreads();
    if (t < 128) meanpart[((size_t)b * HH + y) * CCH + t] = part[0][t] + part[1][t];
}

__global__ void reduce_mean_kernel(const float* __restrict__ meanpart, float* __restrict__ meanbc) {
    int bc = blockIdx.x * 256 + threadIdx.x;     // < 2048
    int b = bc >> 7, c = bc & 127;
    float s = 0.f;
    for (int y = 0; y < HH; ++y) s += meanpart[((size_t)b * HH + y) * CCH + c];
    meanbc[bc] = s * (1.f / (HH * WW));
}

// ---------------- weight transform into swizzled chunk layouts ----------------
__global__ void wt_kernel(const float* __restrict__ w1, const float* __restrict__ w2,
                          bf16* __restrict__ wt1s, bf16* __restrict__ wt2s) {
    const int idx = blockIdx.x * 256 + threadIdx.x;
    const int W1N = (int)WT1S_ELEMS;
    if (idx < W1N) {
        int o = idx & 4095;
        int lo = o & 7, gs = (o >> 3) & 3, row = o >> 5;
        int cg = idx >> 12;                 // 0..215
        int e = cg / 36, c = cg - e * 36;
        int q = c / 9, tap = c - q * 9;
        int g = gs ^ ((row & 3) ^ ((row >> 2) & 3));
        int cin = q * 32 + g * 8 + lo;
        wt1s[idx] = to_bf16(w1[((size_t)(e * CCH + row) * CCH + cin) * 9 + tap]);
    } else if (idx < W1N + (int)WT2S_ELEMS) {
        int j2 = idx - W1N;
        int o = j2 & 4095;
        int lo = o & 7, gs = (o >> 3) & 3, row = o >> 5;
        int cg = j2 >> 12;                  // 0..23
        int e = cg >> 2, kc = cg & 3;
        int g = gs ^ ((row & 3) ^ ((row >> 2) & 3));
        int cin = kc * 32 + g * 8 + lo;
        wt2s[j2] = to_bf16(w2[(size_t)(e * CCH + row) * CCH + cin]);
    }
}

// ---------------- router: parallel logits, then per-b softmax/top-2 (f64, semantics preserved) ----------------
__global__ void router_kernel(const float* __restrict__ meanbc, const float* __restrict__ Wr,
                              const float* __restrict__ br, int* __restrict__ eidx,
                              float* __restrict__ gval, float* __restrict__ total_out) {
    __shared__ double logits_s[BB][EE];
    __shared__ double probs[BB][EE];
    const int t = threadIdx.x;
    if (t < BB * EE) {
        const int b = t / EE, e = t - (t / EE) * EE;
        double s = (double)br[e];
        for (int c = 0; c < CCH; ++c)
            s += (double)meanbc[b * CCH + c] * (double)Wr[c * EE + e];
        if (s > 10.0) s = 10.0;
        if (s < -10.0) s = -10.0;
        logits_s[b][e] = s;
    }
    __syncthreads();
    if (t < BB) {
        const int b = t;
        double mx = logits_s[b][0];
        for (int e = 1; e < EE; ++e) mx = fmax(mx, logits_s[b][e]);
        double den = 0.0, p[EE];
        for (int e = 0; e < EE; ++e) { p[e] = exp(logits_s[b][e] - mx); den += p[e]; }
        for (int e = 0; e < EE; ++e) {
            p[e] /= den;
            if (p[e] < 1e-6) p[e] = 1e-6;
            if (p[e] > 1.0)  p[e] = 1.0;
            probs[b][e] = p[e];
        }
        int e0 = 0;
        for (int e = 1; e < EE; ++e) if (p[e] > p[e0]) e0 = e;
        int e1 = (e0 == 0) ? 1 : 0;
        for (int e = 0; e < EE; ++e) if (e != e0 && p[e] > p[e1]) e1 = e;
        double s2 = p[e0] + p[e1] + 1e-8;
        eidx[b * 2 + 0] = e0;
        eidx[b * 2 + 1] = e1;
        gval[b * 2 + 0] = (float)(p[e0] / s2);
        gval[b * 2 + 1] = (float)(p[e1] / s2);
    }
    __syncthreads();
    if (t == 0) {
        double usage[EE] = {0, 0, 0, 0, 0, 0};
        double ent = 0.0;
        for (int b = 0; b < BB; ++b) {
            double eb = 0.0;
            for (int e = 0; e < EE; ++e) {
                double pv = probs[b][e];
                usage[e] += pv;
                eb -= pv * log(pv + 1e-10);
            }
            ent += eb;
        }
        ent /= (double)BB;
        double lb = 0.0;
        for (int e = 0; e < EE; ++e) {
            double u = usage[e] / (double)BB - 1.0 / (double)EE;
            lb += u * u;
        }
        *total_out = (float)(lb * 5e-4 - ent * 1e-3);
    }
}

// ---------------- fused MoE conv block ----------------
// R6: 512 thr = 8 waves (4 cout-groups x 2 pos-groups); wave = 32 cout x 64 pos,
// acc[2][4] (32 VGPR) + acc1[2][4] (32). Chunk stream: 1 VMEM/chunk/wave; patch:
// exactly 2 VMEM/wave (uniform). Exact vmcnt ledger: W(3) post-patch phase, W(1)
// steady (2-phase slack), W(0) final. XCD-swizzled 1-D grid (2 b's per XCD -> L2-hot weights).
__launch_bounds__(512, 4)
__global__ void moe_conv_kernel(const float* __restrict__ x, const bf16* __restrict__ xp,
                                const bf16* __restrict__ wt1s, const bf16* __restrict__ wt2s,
                                const float* __restrict__ b1, const float* __restrict__ b2,
                                const int* __restrict__ eidx, const float* __restrict__ gval,
                                float* __restrict__ out) {
    __shared__ __align__(16) bf16 Patch[2][180 * 32];   // 23040 B
    __shared__ __align__(16) bf16 Abuf[3][128 * 32];    // 24576 B
    __shared__ __align__(16) bf16 Ht[128 * 128];        // 32768 B  -> 80384 B total

    // XCD-aware remap: assume wgid round-robins XCDs; give each XCD 2 consecutive b's
    const int wgid = blockIdx.x;                 // 0..1151
    const int work = (wgid & 7) * 144 + (wgid >> 3);
    const int b = work / 72;
    const int tile = work - b * 72;
    const int ty = tile / 6, tx = tile - ty * 6;
    const int y0 = ty * 8, x0 = tx * 16;

    const int t = threadIdx.x;
    const int lane = t & 63;
    const int w = t >> 6;                  // 0..7
    const int wcout = w & 3;               // 32-cout group
    const int wpos  = w >> 2;              // 64-pos group
    const int lr = lane & 15;
    const int lh = lane >> 4;              // 0..3
    const int lq = lh * 4;

    const bf16* xpb = xp + (size_t)b * HP * HP * CCH;
    const int e0 = eidx[b * 2 + 0], e1 = eidx[b * 2 + 1];
    const float g0 = gval[b * 2 + 0], g1 = gval[b * 2 + 1];

    auto stream_base = [&](int s) -> const bf16* {                  // s in [0,80)
        int kk = (s >= 40) ? 1 : 0;
        int ss = s - 40 * kk;
        int e = kk ? e1 : e0;
        return (ss < 36) ? wt1s + ((size_t)e * 36 + ss) * 4096
                         : wt2s + ((size_t)e * 4 + (ss - 36)) * 4096;
    };
    auto issue = [&](int s) {                                       // 1 VMEM / wave
        if (s < 80) gload16(stream_base(s) + t * 8, &Abuf[s % 3][0] + w * 512);
    };
    auto patch_dma = [&](int qn, int pb) {                          // exactly 2 VMEM / wave
        bf16* base = &Patch[pb][0];
        {   // it=0: granules 0..511
            int m = t;
            int rp = m >> 2, sl = m & 3;
            int g = sl ^ fsw(rp);
            int py = (rp * 57) >> 10, px = rp - py * 18;
            gload16(xpb + ((size_t)(y0 + py) * HP + (x0 + px)) * CCH + qn * 32 + g * 8,
                    base + w * 512);
        }
        {   // it=1: granules 464..719, wave-pairs duplicate (identical bytes, benign)
            int mb = 464 + (wcout) * 64;        // wave-uniform base granule (w&3)
            int m = mb + lane;
            int rp = m >> 2, sl = m & 3;
            int g = sl ^ fsw(rp);
            int py = (rp * 57) >> 10, px = rp - py * 18;
            gload16(xpb + ((size_t)(y0 + py) * HP + (x0 + px)) * CCH + qn * 32 + g * 8,
                    base + mb * 8);
        }
    };
    auto ldA = [&](int gp, v8bf* dst) {            // 2 A-frags (32 couts)
        const bf16* ab = &Abuf[gp % 3][0];
        #pragma unroll
        for (int i = 0; i < 2; ++i) {
            int r = wcout * 32 + i * 16 + lr;
            dst[i] = *reinterpret_cast<const v8bf*>(&ab[r * 32 + ((lh ^ fsw(r)) << 3)]);
        }
    };

    f32x4 acc1[2][4];
    #pragma unroll
    for (int i = 0; i < 2; ++i)
        #pragma unroll
        for (int j = 0; j < 4; ++j) { f32x4 z = {0.f,0.f,0.f,0.f}; acc1[i][j] = z; }

    // prologue: patch(sec0)->Patch[0], chunks 0,1 in flight
    patch_dma(0, 0);
    issue(0); issue(1);

    int p = 0;
    for (int kk2 = 0; kk2 < 2; ++kk2) {
        const int e = kk2 ? e1 : e0;
        const float g = kk2 ? g1 : g0;

        f32x4 acc[2][4];
        #pragma unroll
        for (int i = 0; i < 2; ++i)
            #pragma unroll
            for (int j = 0; j < 4; ++j) { f32x4 z = {0.f,0.f,0.f,0.f}; acc[i][j] = z; }

        // ---- conv3x3: 36 phases ----
        for (int q = 0; q < 4; ++q) {
            const bf16* pbase = &Patch[q & 1][0];
            #pragma unroll
            for (int tap = 0; tap < 9; ++tap, ++p) {
                // exact ledger: steady [C_p, C_{p+1}] -> W(1); post-patch [C_p,P,P,C_{p+1}] -> W(3)
                if (tap == 1 && !(kk2 == 1 && q == 3)) { WAITVM(3); } else { WAITVM(1); }
                __builtin_amdgcn_s_barrier();
                if (tap == 0 && !(kk2 == 1 && q == 3)) patch_dma((q + 1) & 3, (q + 1) & 1);
                issue(p + 2);

                const int ry = tap / 3, sx = tap - (tap / 3) * 3;
                v8bf af[2], bv[4];
                ldA(p, af);
                #pragma unroll
                for (int j = 0; j < 4; ++j) {
                    int rp = (wpos * 4 + j + ry) * 18 + lr + sx;
                    bv[j] = *reinterpret_cast<const v8bf*>(&pbase[rp * 32 + ((lh ^ fsw(rp)) << 3)]);
                }
                __builtin_amdgcn_s_setprio(1);
                #pragma unroll
                for (int i = 0; i < 2; ++i)
                    #pragma unroll
                    for (int j = 0; j < 4; ++j)
                        acc[i][j] = __builtin_amdgcn_mfma_f32_16x16x32_bf16(af[i], bv[j], acc[i][j], 0, 0, 0);
                __builtin_amdgcn_s_setprio(0);
            }
        }

        // ---- gelu(acc + b1) * g -> Ht (acc dies) ----
        const float* b1e = b1 + e * CCH;
        #pragma unroll
        for (int i = 0; i < 2; ++i) {
            const int cb = wcout * 32 + i * 16 + lq;
            float bias[4];
            #pragma unroll
            for (int q2 = 0; q2 < 4; ++q2) bias[q2] = b1e[cb + q2];
            #pragma unroll
            for (int j = 0; j < 4; ++j) {
                const int pos = wpos * 64 + j * 16 + lr;
                bf16 hv[4];
                #pragma unroll
                for (int q2 = 0; q2 < 4; ++q2) {
                    float v = acc[i][j][q2] + bias[q2];
                    float u = 0.7978845608028654f * (v + 0.044715f * v * v * v);
                    float ex = __expf(2.f * u);
                    float th = (ex - 1.f) / (ex + 1.f);
                    hv[q2] = to_bf16(g * (0.5f * v * (1.f + th)));
                }
                const int slot = (cb >> 3) ^ (pos & 7);
                *reinterpret_cast<uint2*>(&Ht[pos * 128 + slot * 8 + (cb & 7)]) =
                    *reinterpret_cast<uint2*>(hv);
            }
        }
        WAITLGKM0;                         // Ht writes drained; published by next barrier

        // ---- conv1x1: 4 phases ----
        #pragma unroll
        for (int kc = 0; kc < 4; ++kc, ++p) {
            if (kk2 == 1 && kc == 3) { WAITVM(0); } else { WAITVM(1); }
            __builtin_amdgcn_s_barrier();
            issue(p + 2);

            v8bf af[2], bv[4];
            ldA(p, af);
            #pragma unroll
            for (int j = 0; j < 4; ++j) {
                int pos = wpos * 64 + j * 16 + lr;
                int gr = kc * 4 + lh;
                bv[j] = *reinterpret_cast<const v8bf*>(&Ht[pos * 128 + ((gr ^ (pos & 7)) << 3)]);
            }
            __builtin_amdgcn_s_setprio(1);
            #pragma unroll
            for (int i = 0; i < 2; ++i)
                #pragma unroll
                for (int j = 0; j < 4; ++j)
                    acc1[i][j] = __builtin_amdgcn_mfma_f32_16x16x32_bf16(af[i], bv[j], acc1[i][j], 0, 0, 0);
            __builtin_amdgcn_s_setprio(0);
        }
    }

    // ---- epilogue: out = acc1 + (g0*b2[e0] + g1*b2[e1]) + (g0+g1)*x ----
    const float gsum = g0 + g1;
    #pragma unroll
    for (int i = 0; i < 2; ++i) {
        const int cb = wcout * 32 + i * 16 + lq;
        float bs[4];
        #pragma unroll
        for (int q2 = 0; q2 < 4; ++q2)
            bs[q2] = g0 * b2[e0 * CCH + cb + q2] + g1 * b2[e1 * CCH + cb + q2];
        #pragma unroll
        for (int j = 0; j < 4; ++j) {
            const int pos = wpos * 64 + j * 16 + lr;
            const int yy = pos >> 4, xx = pos & 15;
            #pragma unroll
            for (int q2 = 0; q2 < 4; ++q2) {
                size_t gi = (((size_t)b * CCH + cb + q2) * HH + (y0 + yy)) * WW + (x0 + xx);
                out[gi] = acc1[i][j][q2] + bs[q2] + gsum * x[gi];
            }
        }
    }
}

extern "C" void kernel_launch(void* const* d_in, const int* in_sizes, int n_in,
                              void* d_out, int out_size, void* d_ws, size_t ws_size,
                              hipStream_t stream) {
    const float* x  = (const float*)d_in[0];
    const float* Wr = (const float*)d_in[1];
    const float* br = (const float*)d_in[2];
    const float* W1 = (const float*)d_in[3];
    const float* b1 = (const float*)d_in[4];
    const float* W2 = (const float*)d_in[5];
    const float* b2 = (const float*)d_in[6];
    float* out = (float*)d_out;

    char* ws = (char*)d_ws;
    bf16* xp    = (bf16*)ws;
    bf16* wt1s  = (bf16*)(ws + XP_BYTES);
    bf16* wt2s  = (bf16*)(ws + XP_BYTES + WT1S_BYTES);
    float* meanpart = (float*)(ws + XP_BYTES + WT1S_BYTES + WT2S_BYTES);
    float* meanbc   = (float*)(ws + XP_BYTES + WT1S_BYTES + WT2S_BYTES + (size_t)BB * HH * CCH * 4);
    int*   eidx     = (int*)(ws + XP_BYTES + WT1S_BYTES + WT2S_BYTES + (size_t)BB * HH * CCH * 4 + BB * CCH * 4);
    float* gvals    = (float*)(ws + XP_BYTES + WT1S_BYTES + WT2S_BYTES + (size_t)BB * HH * CCH * 4 + BB * CCH * 4 + BB * 2 * 4);
    float* total    = out + (size_t)BB * CCH * HH * WW;

    border_kernel<<<BB, 256, 0, stream>>>(xp);
    pad_kernel<<<dim3(HH, BB), 256, 0, stream>>>(x, xp, meanpart);
    reduce_mean_kernel<<<8, 256, 0, stream>>>(meanpart, meanbc);
    wt_kernel<<<(unsigned)((WT1S_ELEMS + WT2S_ELEMS + 255) / 256), 256, 0, stream>>>(W1, W2, wt1s, wt2s);
    router_kernel<<<1, 128, 0, stream>>>(meanbc, Wr, br, eidx, gvals, total);
    moe_conv_kernel<<<1152, 512, 0, stream>>>(x, xp, wt1s, wt2s, b1, b2, eidx, gvals, out);
}